// Round 1
// baseline (646.051 us; speedup 1.0000x reference)
//
#include <hip/hip_runtime.h>
#include <math.h>

namespace {
constexpr int BATCH = 4096;
constexpr int SEQT  = 256;
constexpr int INSZ  = 24;
constexpr int H     = 40;
constexpr int NOUT  = 24;
constexpr int R     = 16;        // batch rows per block -> grid = 256
constexpr int NT    = 320;       // threads per block (5 waves)
constexpr int KTOT  = H + INSZ;  // 64: concat [h(40) | x(24)]
constexpr int KP    = 68;        // padded LDS row stride in floats (16B-aligned, bank-spread)

__device__ __forceinline__ float4 ld4(const float* p) {
  return *reinterpret_cast<const float4*>(p);
}
__device__ __forceinline__ float dot4(const float4 a, const float4 b, float acc) {
  acc = fmaf(a.x, b.x, acc);
  acc = fmaf(a.y, b.y, acc);
  acc = fmaf(a.z, b.z, acc);
  return fmaf(a.w, b.w, acc);
}
__device__ __forceinline__ float sigm(float v) {
  return 1.0f / (1.0f + __expf(-v));
}
__device__ __forceinline__ float tanh_fast(float v) {
  // safe at +/-inf arguments: exp(-2v) -> 0 or inf, result -> +/-1
  return 2.0f / (1.0f + __expf(-2.0f * v)) - 1.0f;
}
}  // namespace

__global__ __launch_bounds__(NT) void gru_fused_kernel(
    const float* __restrict__ x, const float* __restrict__ Wih,
    const float* __restrict__ Whh, const float* __restrict__ bih,
    const float* __restrict__ bhh, const float* __restrict__ Wfc,
    const float* __restrict__ bfc, float* __restrict__ out,
    float* __restrict__ hid) {
  // Weights reordered unit-major: row 3u+g (g: 0=r,1=z,2=n), cols [0,40)=W_hh, [40,64)=W_ih
  __shared__ float Wc[3 * H][KP];
  __shared__ float hx[2][R][KP];     // double-buffered [h(40) | x_t(24)] per row
  __shared__ float WfcL[NOUT][H];
  __shared__ float bfcL[NOUT];

  const int tid = threadIdx.x;
  const int gb0 = blockIdx.x * R;

  // ---- stage weights to LDS ----
  for (int idx = tid; idx < 3 * H * KTOT; idx += NT) {
    const int row = idx >> 6;           // idx / 64
    const int k   = idx & 63;
    const int u   = row / 3;
    const int g   = row - u * 3;
    const int src = g * H + u;          // original gate-row index in W_ih/W_hh
    Wc[row][k] = (k < H) ? Whh[src * H + k] : Wih[src * INSZ + (k - H)];
  }
  for (int idx = tid; idx < NOUT * H; idx += NT) {
    WfcL[idx / H][idx % H] = Wfc[idx];
  }
  if (tid < NOUT) bfcL[tid] = bfc[tid];

  // ---- init hx[0]: h = 0, x-part = x(t=0) ----
  for (int idx = tid; idx < R * H; idx += NT) {
    hx[0][idx / H][idx % H] = 0.0f;
  }
  if (tid < R * (INSZ / 4)) {           // 16 rows * 6 float4 = 96 loads
    const int b = tid / 6;
    const int j = (tid - b * 6) * 4;
    *reinterpret_cast<float4*>(&hx[0][b][H + j]) =
        ld4(x + ((size_t)(gb0 + b) * SEQT + 0) * INSZ + j);
  }

  // per-thread ownership: unit u (all 3 gates), row pair (b0, b1)
  const int u  = tid >> 3;              // 0..39
  const int bg = tid & 7;               // 0..7
  const int b0 = bg * 2;
  const int b1 = b0 + 1;
  const float rb   = bih[u] + bhh[u];
  const float zbi  = bih[H + u] + bhh[H + u];
  const float nb_h = bhh[2 * H + u];    // kept separate: r multiplies (h-proj + b_hh_n)
  const float nb_x = bih[2 * H + u];

  const float* wr = &Wc[u * 3 + 0][0];
  const float* wz = &Wc[u * 3 + 1][0];
  const float* wn = &Wc[u * 3 + 2][0];

  __syncthreads();

  for (int t = 0; t < SEQT; ++t) {
    const int p = t & 1;
    const float* cur = &hx[p][0][0];
    float* nxt = &hx[p ^ 1][0][0];

    // ---- phase A: gate pre-activation dots (reads cur) ----
    float ar0 = rb,   ar1 = rb;
    float az0 = zbi,  az1 = zbi;
    float ah0 = nb_h, ah1 = nb_h;
    float ax0 = nb_x, ax1 = nb_x;
    const float* c0 = cur + b0 * KP;
    const float* c1 = cur + b1 * KP;
#pragma unroll
    for (int k = 0; k < H; k += 4) {      // h-projection part
      const float4 wrv = ld4(wr + k);
      const float4 wzv = ld4(wz + k);
      const float4 wnv = ld4(wn + k);
      const float4 h0 = ld4(c0 + k);
      const float4 h1 = ld4(c1 + k);
      ar0 = dot4(wrv, h0, ar0); ar1 = dot4(wrv, h1, ar1);
      az0 = dot4(wzv, h0, az0); az1 = dot4(wzv, h1, az1);
      ah0 = dot4(wnv, h0, ah0); ah1 = dot4(wnv, h1, ah1);
    }
#pragma unroll
    for (int k = H; k < KTOT; k += 4) {   // x-projection part
      const float4 wrv = ld4(wr + k);
      const float4 wzv = ld4(wz + k);
      const float4 wnv = ld4(wn + k);
      const float4 x0 = ld4(c0 + k);
      const float4 x1 = ld4(c1 + k);
      ar0 = dot4(wrv, x0, ar0); ar1 = dot4(wrv, x1, ar1);
      az0 = dot4(wzv, x0, az0); az1 = dot4(wzv, x1, az1);
      ax0 = dot4(wnv, x0, ax0); ax1 = dot4(wnv, x1, ax1);
    }
    const float hold0 = c0[u];
    const float hold1 = c1[u];

    // ---- gate math ----
    const float r0 = sigm(ar0), r1 = sigm(ar1);
    const float z0 = sigm(az0), z1 = sigm(az1);
    const float n0 = tanh_fast(ax0 + r0 * ah0);
    const float n1 = tanh_fast(ax1 + r1 * ah1);
    const float hn0 = (1.0f - z0) * n0 + z0 * hold0;
    const float hn1 = (1.0f - z1) * n1 + z1 * hold1;

    // ---- phase B: write h_new + x(t+1) into nxt ----
    nxt[b0 * KP + u] = hn0;
    nxt[b1 * KP + u] = hn1;
    if (tid < R * (INSZ / 4) && t + 1 < SEQT) {
      const int b = tid / 6;
      const int j = (tid - b * 6) * 4;
      *reinterpret_cast<float4*>(nxt + b * KP + H + j) =
          ld4(x + ((size_t)(gb0 + b) * SEQT + (t + 1)) * INSZ + j);
    }

    __syncthreads();

    // ---- phase C: FC + sigmoid + store (reads nxt h-part) ----
    for (int idx = tid; idx < R * NOUT; idx += NT) {
      const int b = idx / NOUT;
      const int o = idx - b * NOUT;
      const float* hrow = nxt + b * KP;
      const float* wrow = &WfcL[o][0];
      float acc = bfcL[o];
#pragma unroll
      for (int k = 0; k < H; k += 4) {
        acc = dot4(ld4(wrow + k), ld4(hrow + k), acc);
      }
      out[((size_t)(gb0 + b) * SEQT + t) * NOUT + o] = sigm(acc);
    }
    // no barrier needed here: next phase A/B only read/write buffers that are
    // read-only / untouched between this point and the next __syncthreads
  }

  // ---- final hidden state: after even T, latest h lives in hx[0] ----
  for (int idx = tid; idx < R * H; idx += NT) {
    const int b = idx / H;
    const int k = idx - b * H;
    hid[(size_t)(gb0 + b) * H + k] = hx[0][b][k];
  }
}

extern "C" void kernel_launch(void* const* d_in, const int* in_sizes, int n_in,
                              void* d_out, int out_size, void* d_ws, size_t ws_size,
                              hipStream_t stream) {
  const float* x   = (const float*)d_in[0];
  const float* Wih = (const float*)d_in[1];
  const float* Whh = (const float*)d_in[2];
  const float* bih = (const float*)d_in[3];
  const float* bhh = (const float*)d_in[4];
  const float* Wfc = (const float*)d_in[5];
  const float* bfc = (const float*)d_in[6];
  float* out = (float*)d_out;
  float* hid = out + (size_t)BATCH * SEQT * NOUT;

  dim3 grid(BATCH / R);
  dim3 block(NT);
  hipLaunchKernelGGL(gru_fused_kernel, grid, block, 0, stream,
                     x, Wih, Whh, bih, bhh, Wfc, bfc, out, hid);
}

// Round 2
// 582.883 us; speedup vs baseline: 1.1084x; 1.1084x over previous
//
#include <hip/hip_runtime.h>
#include <math.h>

namespace {
constexpr int BATCH = 4096;
constexpr int SEQT  = 256;
constexpr int INSZ  = 24;
constexpr int H     = 40;
constexpr int NOUT  = 24;
constexpr int R     = 16;        // batch rows per block -> grid = 256 (1 block/CU)
constexpr int NT    = 320;       // threads per block (5 waves)
constexpr int KTOT  = H + INSZ;  // 64: concat [h(40) | x(24)]
constexpr int KP    = 68;        // LDS row stride: 2*KP%32==8 -> even rows spread, ~2-way (free)
constexpr int KFC   = 44;        // FC weight LDS stride: breaks 4-way conflict of stride 40

__device__ __forceinline__ float4 ld4(const float* p) {
  return *reinterpret_cast<const float4*>(p);
}
__device__ __forceinline__ float dot4(const float4 a, const float4 b, float acc) {
  acc = fmaf(a.x, b.x, acc);
  acc = fmaf(a.y, b.y, acc);
  acc = fmaf(a.z, b.z, acc);
  return fmaf(a.w, b.w, acc);
}
__device__ __forceinline__ float sigm(float v) {
  return 1.0f / (1.0f + __expf(-v));
}
__device__ __forceinline__ float tanh_fast(float v) {
  return 2.0f / (1.0f + __expf(-2.0f * v)) - 1.0f;
}
}  // namespace

__global__ __launch_bounds__(NT, 2) void gru_fused_kernel(
    const float* __restrict__ x, const float* __restrict__ Wih,
    const float* __restrict__ Whh, const float* __restrict__ bih,
    const float* __restrict__ bhh, const float* __restrict__ Wfc,
    const float* __restrict__ bfc, float* __restrict__ out,
    float* __restrict__ hid) {
  __shared__ float hx[2][R][KP];     // double-buffered [h(40) | x_t(24)] per row
  __shared__ float WfcL[NOUT][KFC];
  __shared__ float bfcL[NOUT];

  const int tid = threadIdx.x;
  const int gb0 = blockIdx.x * R;

  // ---- stage FC weights to LDS ----
  for (int idx = tid; idx < NOUT * H; idx += NT) {
    WfcL[idx / H][idx % H] = Wfc[idx];
  }
  if (tid < NOUT) bfcL[tid] = bfc[tid];

  // ---- init hx[0]: h = 0, x-part = x(t=0) ----
  for (int idx = tid; idx < R * H; idx += NT) {
    hx[0][idx / H][idx % H] = 0.0f;
  }
  if (tid < R * (INSZ / 4)) {           // 16 rows * 6 float4
    const int b = tid / 6;
    const int j = (tid - b * 6) * 4;
    *reinterpret_cast<float4*>(&hx[0][b][H + j]) =
        ld4(x + ((size_t)(gb0 + b) * SEQT + 0) * INSZ + j);
  }

  // per-thread ownership: unit u (all 3 gates), row pair (b0, b1)
  const int u  = tid >> 3;              // 0..39
  const int bg = tid & 7;               // 0..7
  const int b0 = bg * 2;
  const int b1 = b0 + 1;
  const float rb   = bih[u] + bhh[u];
  const float zbi  = bih[H + u] + bhh[H + u];
  const float nb_h = bhh[2 * H + u];
  const float nb_x = bih[2 * H + u];

  // ---- weights in registers: 3 gate rows, cols [0,40)=W_hh, [40,64)=W_ih ----
  // k4 index 0..9 -> Whh chunk, 10..15 -> Wih chunk (40 = 4*10 aligns exactly)
  float4 Wr[16], Wz[16], Wn[16];
  {
    const float* hr = Whh + (0 * H + u) * H;   // gate r
    const float* hz = Whh + (1 * H + u) * H;
    const float* hn = Whh + (2 * H + u) * H;
    const float* ir = Wih + (0 * H + u) * INSZ;
    const float* iz = Wih + (1 * H + u) * INSZ;
    const float* in_ = Wih + (2 * H + u) * INSZ;
#pragma unroll
    for (int k4 = 0; k4 < 10; ++k4) {
      Wr[k4] = ld4(hr + 4 * k4);
      Wz[k4] = ld4(hz + 4 * k4);
      Wn[k4] = ld4(hn + 4 * k4);
    }
#pragma unroll
    for (int k4 = 10; k4 < 16; ++k4) {
      Wr[k4] = ld4(ir + 4 * (k4 - 10));
      Wz[k4] = ld4(iz + 4 * (k4 - 10));
      Wn[k4] = ld4(in_ + 4 * (k4 - 10));
    }
  }

  __syncthreads();

  for (int t = 0; t < SEQT; ++t) {
    const int p = t & 1;
    const float* cur = &hx[p][0][0];
    float* nxt = &hx[p ^ 1][0][0];

    // ---- phase A: gate pre-activation dots (reads cur; weights in regs) ----
    float ar0 = rb,   ar1 = rb;
    float az0 = zbi,  az1 = zbi;
    float ah0 = nb_h, ah1 = nb_h;
    float ax0 = nb_x, ax1 = nb_x;
    const float* c0 = cur + b0 * KP;
    const float* c1 = cur + b1 * KP;
#pragma unroll
    for (int k4 = 0; k4 < 16; ++k4) {
      const float4 v0 = ld4(c0 + 4 * k4);
      const float4 v1 = ld4(c1 + 4 * k4);
      ar0 = dot4(Wr[k4], v0, ar0); ar1 = dot4(Wr[k4], v1, ar1);
      az0 = dot4(Wz[k4], v0, az0); az1 = dot4(Wz[k4], v1, az1);
      if (k4 < 10) { ah0 = dot4(Wn[k4], v0, ah0); ah1 = dot4(Wn[k4], v1, ah1); }
      else         { ax0 = dot4(Wn[k4], v0, ax0); ax1 = dot4(Wn[k4], v1, ax1); }
    }
    const float hold0 = c0[u];
    const float hold1 = c1[u];

    // ---- gate math ----
    const float r0 = sigm(ar0), r1 = sigm(ar1);
    const float z0 = sigm(az0), z1 = sigm(az1);
    const float n0 = tanh_fast(ax0 + r0 * ah0);
    const float n1 = tanh_fast(ax1 + r1 * ah1);
    const float hn0 = (1.0f - z0) * n0 + z0 * hold0;
    const float hn1 = (1.0f - z1) * n1 + z1 * hold1;

    // ---- phase B: write h_new + x(t+1) into nxt ----
    nxt[b0 * KP + u] = hn0;
    nxt[b1 * KP + u] = hn1;
    if (tid < R * (INSZ / 4) && t + 1 < SEQT) {
      const int b = tid / 6;
      const int j = (tid - b * 6) * 4;
      *reinterpret_cast<float4*>(nxt + b * KP + H + j) =
          ld4(x + ((size_t)(gb0 + b) * SEQT + (t + 1)) * INSZ + j);
    }

    __syncthreads();

    // ---- phase C: FC + sigmoid + store (reads nxt h-part) ----
    for (int idx = tid; idx < R * NOUT; idx += NT) {
      const int b = idx / NOUT;
      const int o = idx - b * NOUT;
      const float* hrow = nxt + b * KP;
      const float* wrow = &WfcL[o][0];
      float acc = bfcL[o];
#pragma unroll
      for (int k = 0; k < H; k += 4) {
        acc = dot4(ld4(wrow + k), ld4(hrow + k), acc);
      }
      out[((size_t)(gb0 + b) * SEQT + t) * NOUT + o] = sigm(acc);
    }
    // next phase A reads nxt (as cur) after this; phase B of next iter writes
    // the OTHER buffer; no extra barrier needed.
  }

  // ---- final hidden state: after even T, latest h lives in hx[0] ----
  for (int idx = tid; idx < R * H; idx += NT) {
    const int b = idx / H;
    const int k = idx - b * H;
    hid[(size_t)(gb0 + b) * H + k] = hx[0][b][k];
  }
}

extern "C" void kernel_launch(void* const* d_in, const int* in_sizes, int n_in,
                              void* d_out, int out_size, void* d_ws, size_t ws_size,
                              hipStream_t stream) {
  const float* x   = (const float*)d_in[0];
  const float* Wih = (const float*)d_in[1];
  const float* Whh = (const float*)d_in[2];
  const float* bih = (const float*)d_in[3];
  const float* bhh = (const float*)d_in[4];
  const float* Wfc = (const float*)d_in[5];
  const float* bfc = (const float*)d_in[6];
  float* out = (float*)d_out;
  float* hid = out + (size_t)BATCH * SEQT * NOUT;

  dim3 grid(BATCH / R);
  dim3 block(NT);
  hipLaunchKernelGGL(gru_fused_kernel, grid, block, 0, stream,
                     x, Wih, Whh, bih, bhh, Wfc, bfc, out, hid);
}

// Round 3
// 264.685 us; speedup vs baseline: 2.4408x; 2.2022x over previous
//
#include <hip/hip_runtime.h>
#include <math.h>

typedef __attribute__((ext_vector_type(8))) short short8;
typedef __attribute__((ext_vector_type(4))) float f32x4;

namespace {
constexpr int BATCH = 4096;
constexpr int SEQT  = 256;
constexpr int INSZ  = 24;
constexpr int H     = 40;
constexpr int NOUT  = 24;
constexpr int R     = 16;    // batch rows per block (M dim), grid = 256
constexpr int NT    = 512;   // 8 waves
constexpr int PSTR  = 164;   // preact LDS stride (f32) -> <=2-way banks
constexpr int HSTR  = 44;    // h fp32 LDS stride

__device__ __forceinline__ unsigned short f2bf(float f) {
  unsigned int u = __float_as_uint(f);
  unsigned int r = (u + 0x7FFFu + ((u >> 16) & 1u)) >> 16;  // RNE
  return (unsigned short)r;
}
__device__ __forceinline__ float4 ld4(const float* p) {
  return *reinterpret_cast<const float4*>(p);
}
__device__ __forceinline__ float sigm(float v) { return 1.0f / (1.0f + __expf(-v)); }
__device__ __forceinline__ float tanh_fast(float v) {
  return 2.0f / (1.0f + __expf(-2.0f * v)) - 1.0f;
}

// Concatenated gate matrix Wcat[k][col], k: 0..23 = x-cols (Wih), 24..63 = h-cols (Whh).
// col zones: [0,40)=r, [40,80)=z (orig row index == col); [80,120)=n_x (x part only);
// [120,160)=n_h (h part only).
__device__ __forceinline__ float wcat(const float* Wih, const float* Whh, int col, int k) {
  if (col < 80)  return (k < 24) ? Wih[col * 24 + k] : Whh[col * 40 + (k - 24)];
  if (col < 120) return (k < 24) ? Wih[col * 24 + k] : 0.0f;            // n_x
  return (k < 24) ? 0.0f : Whh[(col - 40) * 40 + (k - 24)];             // n_h
}
__device__ __forceinline__ float gbias(const float* bih, const float* bhh, int col) {
  if (col < 80)  return bih[col] + bhh[col];
  if (col < 120) return bih[col];        // n_x gets b_ih_n
  return bhh[col - 40];                  // n_h gets b_hh_n (multiplied by r later)
}
__device__ __forceinline__ short8 buildB(const float* Wih, const float* Whh,
                                         int col, int kt, int lq) {
  short8 b;
#pragma unroll
  for (int j = 0; j < 8; ++j) {
    const int k = kt * 32 + lq * 8 + j;
    b[j] = (short)f2bf(wcat(Wih, Whh, col, k));
  }
  return b;
}
__device__ __forceinline__ short8 buildFC(const float* Wfc, int o, int kt, int lq) {
  short8 b;
#pragma unroll
  for (int j = 0; j < 8; ++j) {
    const int k = kt * 32 + lq * 8 + j;
    float v = (o < NOUT && k >= 24) ? Wfc[o * H + (k - 24)] : 0.0f;  // k<24 (x rows) => 0
    b[j] = (short)f2bf(v);
  }
  return b;
}
}  // namespace

__global__ __launch_bounds__(NT) void gru_mfma_kernel(
    const float* __restrict__ x, const float* __restrict__ Wih,
    const float* __restrict__ Whh, const float* __restrict__ bih,
    const float* __restrict__ bhh, const float* __restrict__ Wfc,
    const float* __restrict__ bfc, float* __restrict__ out,
    float* __restrict__ hid) {
  // A operand: hx in bf16, [16 rows][64 k] per buffer, XOR-swizzled (idx ^= (row&7)<<3)
  __shared__ __align__(16) unsigned short Abuf[2 * 1024];
  __shared__ float preact[16 * PSTR];   // gate pre-activations, cols 0..159
  __shared__ float hbuf[16 * HSTR];     // fp32 hidden state

  const int tid = threadIdx.x;
  const int l  = tid & 63;
  const int w  = tid >> 6;       // wave 0..7
  const int lm = l & 15;         // MFMA: A-row / B-col / D-col
  const int lq = l >> 4;         // MFMA k-chunk / D row-group
  const int gb0 = blockIdx.x * R;

  // ---- zero LDS state ----
  for (int i = tid; i < 2 * 1024; i += NT) Abuf[i] = 0;
  for (int i = tid; i < 16 * HSTR; i += NT) hbuf[i] = 0.0f;

  // ---- A-fragment LDS addresses (ushort idx), fixed per lane ----
  const int aBase0 = ((lm * 64 + lq * 8)      ^ ((lm & 7) << 3));  // k-tile 0
  const int aBase1 = ((lm * 64 + lq * 8 + 32) ^ ((lm & 7) << 3));  // k-tile 1

  // ---- B fragments (weights) in registers; bias per owned column ----
  const int colA = w * 16 + lm;                 // tiles 0..7
  const short8 BA0 = buildB(Wih, Whh, colA, 0, lq);
  const short8 BA1 = buildB(Wih, Whh, colA, 1, lq);
  const float biasA = gbias(bih, bhh, colA);

  short8 BB0, BB1; float biasB = 0.0f;
  const int colB = (8 + w) * 16 + lm;           // tiles 8,9 -> waves 0,1
  if (w < 2) {
    BB0 = buildB(Wih, Whh, colB, 0, lq);
    BB1 = buildB(Wih, Whh, colB, 1, lq);
    biasB = gbias(bih, bhh, colB);
  }

  // ---- FC fragments: waves 2 (cols 0..15) and 3 (cols 16..23) ----
  short8 F0, F1; float biasF = 0.0f; int oc = 32;
  size_t outBase = 0;
  if (w == 2 || w == 3) {
    oc = (w - 2) * 16 + lm;
    F0 = buildFC(Wfc, oc, 0, lq);
    F1 = buildFC(Wfc, oc, 1, lq);
    biasF = (oc < NOUT) ? bfc[oc] : 0.0f;
    outBase = ((size_t)(gb0 + lq * 4) * SEQT) * NOUT + oc;
  }

  // ---- gate-math item mapping: item i -> (row=i/40, u=i%40), 640 items ----
  const int i1 = tid;           const int r1 = i1 / 40, u1 = i1 - 40 * r1;
  const int i2 = 512 + tid;     const int r2 = i2 / 40, u2 = i2 - 40 * r2;  // tid<128
  const int aw1 = ((r1 * 64 + 24 + u1) ^ ((r1 & 7) << 3));
  const int aw2 = ((r2 * 64 + 24 + u2) ^ ((r2 & 7) << 3));

  // ---- x staging: 96 threads, one float4 (4 x-cols) each ----
  const int xrow = tid / 6, xj = (tid - (tid / 6) * 6) * 4;
  const float* xptr = x + ((size_t)(gb0 + xrow) * SEQT) * INSZ + xj;
  const int xw = ((xrow * 64 + xj) ^ ((xrow & 7) << 3));  // x occupies k 0..23

  __syncthreads();  // zero-init done before x(0) write

  if (tid < 96) {   // stage x(t=0) into buffer 0
    const float4 xv = ld4(xptr);
    unsigned int p0 = (unsigned int)f2bf(xv.x) | ((unsigned int)f2bf(xv.y) << 16);
    unsigned int p1 = (unsigned int)f2bf(xv.z) | ((unsigned int)f2bf(xv.w) << 16);
    *reinterpret_cast<uint2*>(&Abuf[xw]) = make_uint2(p0, p1);
  }
  __syncthreads();

  for (int t = 0; t < SEQT; ++t) {
    const int bo  = (t & 1) << 10;   // current buffer (ushort offset)
    const int nbo = bo ^ 1024;       // next buffer

    // ---- gate GEMM: D[16 x 160] = A[16 x 64] * Wcat ----
    {
      const short8 A0 = *reinterpret_cast<const short8*>(&Abuf[bo + aBase0]);
      const short8 A1 = *reinterpret_cast<const short8*>(&Abuf[bo + aBase1]);
      f32x4 acc = {biasA, biasA, biasA, biasA};
      acc = __builtin_amdgcn_mfma_f32_16x16x32_bf16(A0, BA0, acc, 0, 0, 0);
      acc = __builtin_amdgcn_mfma_f32_16x16x32_bf16(A1, BA1, acc, 0, 0, 0);
      preact[(lq * 4 + 0) * PSTR + colA] = acc[0];
      preact[(lq * 4 + 1) * PSTR + colA] = acc[1];
      preact[(lq * 4 + 2) * PSTR + colA] = acc[2];
      preact[(lq * 4 + 3) * PSTR + colA] = acc[3];
      if (w < 2) {
        f32x4 acc2 = {biasB, biasB, biasB, biasB};
        acc2 = __builtin_amdgcn_mfma_f32_16x16x32_bf16(A0, BB0, acc2, 0, 0, 0);
        acc2 = __builtin_amdgcn_mfma_f32_16x16x32_bf16(A1, BB1, acc2, 0, 0, 0);
        preact[(lq * 4 + 0) * PSTR + colB] = acc2[0];
        preact[(lq * 4 + 1) * PSTR + colB] = acc2[1];
        preact[(lq * 4 + 2) * PSTR + colB] = acc2[2];
        preact[(lq * 4 + 3) * PSTR + colB] = acc2[3];
      }
    }
    __syncthreads();  // barrier1: preact ready

    // ---- gate elementwise: h_new = (1-z)*n + z*h ----
    {
      const float pr = preact[r1 * PSTR + u1];
      const float pz = preact[r1 * PSTR + 40 + u1];
      const float px = preact[r1 * PSTR + 80 + u1];
      const float ph = preact[r1 * PSTR + 120 + u1];
      const float hold = hbuf[r1 * HSTR + u1];
      const float rr = sigm(pr), zz = sigm(pz);
      const float nn = tanh_fast(px + rr * ph);
      const float h = (1.0f - zz) * nn + zz * hold;
      hbuf[r1 * HSTR + u1] = h;
      Abuf[nbo + aw1] = f2bf(h);
    }
    if (tid < 128) {
      const float pr = preact[r2 * PSTR + u2];
      const float pz = preact[r2 * PSTR + 40 + u2];
      const float px = preact[r2 * PSTR + 80 + u2];
      const float ph = preact[r2 * PSTR + 120 + u2];
      const float hold = hbuf[r2 * HSTR + u2];
      const float rr = sigm(pr), zz = sigm(pz);
      const float nn = tanh_fast(px + rr * ph);
      const float h = (1.0f - zz) * nn + zz * hold;
      hbuf[r2 * HSTR + u2] = h;
      Abuf[nbo + aw2] = f2bf(h);
    }
    if (tid < 96 && t + 1 < SEQT) {  // stage x(t+1) into next buffer
      const float4 xv = ld4(xptr + (size_t)(t + 1) * INSZ);
      unsigned int p0 = (unsigned int)f2bf(xv.x) | ((unsigned int)f2bf(xv.y) << 16);
      unsigned int p1 = (unsigned int)f2bf(xv.z) | ((unsigned int)f2bf(xv.w) << 16);
      *reinterpret_cast<uint2*>(&Abuf[nbo + xw]) = make_uint2(p0, p1);
    }
    __syncthreads();  // barrier2: h_new (bf16+fp32) ready

    // ---- FC on h_new (waves 2,3); x rows of F are zero so stale x is harmless ----
    if (w == 2 || w == 3) {
      const short8 hA0 = *reinterpret_cast<const short8*>(&Abuf[nbo + aBase0]);
      const short8 hA1 = *reinterpret_cast<const short8*>(&Abuf[nbo + aBase1]);
      f32x4 fa = {biasF, biasF, biasF, biasF};
      fa = __builtin_amdgcn_mfma_f32_16x16x32_bf16(hA0, F0, fa, 0, 0, 0);
      fa = __builtin_amdgcn_mfma_f32_16x16x32_bf16(hA1, F1, fa, 0, 0, 0);
      if (oc < NOUT) {
        const size_t base = outBase + (size_t)t * NOUT;
        constexpr size_t RS = (size_t)SEQT * NOUT;
        out[base + 0 * RS] = sigm(fa[0]);
        out[base + 1 * RS] = sigm(fa[1]);
        out[base + 2 * RS] = sigm(fa[2]);
        out[base + 3 * RS] = sigm(fa[3]);
      }
    }
  }

  __syncthreads();
  // ---- final hidden state (fp32) ----
  hid[(size_t)(gb0 + r1) * H + u1] = hbuf[r1 * HSTR + u1];
  if (tid < 128) hid[(size_t)(gb0 + r2) * H + u2] = hbuf[r2 * HSTR + u2];
}

extern "C" void kernel_launch(void* const* d_in, const int* in_sizes, int n_in,
                              void* d_out, int out_size, void* d_ws, size_t ws_size,
                              hipStream_t stream) {
  const float* x   = (const float*)d_in[0];
  const float* Wih = (const float*)d_in[1];
  const float* Whh = (const float*)d_in[2];
  const float* bih = (const float*)d_in[3];
  const float* bhh = (const float*)d_in[4];
  const float* Wfc = (const float*)d_in[5];
  const float* bfc = (const float*)d_in[6];
  float* out = (float*)d_out;
  float* hid = out + (size_t)BATCH * SEQT * NOUT;

  dim3 grid(BATCH / R);
  dim3 block(NT);
  hipLaunchKernelGGL(gru_mfma_kernel, grid, block, 0, stream,
                     x, Wih, Whh, bih, bhh, Wfc, bfc, out, hid);
}

// Round 4
// 183.429 us; speedup vs baseline: 3.5221x; 1.4430x over previous
//
#include <hip/hip_runtime.h>
#include <math.h>

typedef __attribute__((ext_vector_type(8))) short short8;
typedef __attribute__((ext_vector_type(4))) float f32x4;

namespace {
constexpr int BATCH = 4096;
constexpr int SEQT  = 256;
constexpr int INSZ  = 24;
constexpr int H     = 40;
constexpr int NOUT  = 24;
constexpr int R     = 16;    // batch rows per block, grid = 256 (1 block/CU)
constexpr int NT    = 256;   // 4 waves: 0-2 gate (u-ranges), 3 FC + x staging

__device__ __forceinline__ unsigned short f2bf(float f) {
  unsigned int u = __float_as_uint(f);
  return (unsigned short)((u + 0x7FFFu + ((u >> 16) & 1u)) >> 16);  // RNE
}
__device__ __forceinline__ float4 ld4(const float* p) {
  return *reinterpret_cast<const float4*>(p);
}
__device__ __forceinline__ float sigm(float v) { return 1.0f / (1.0f + __expf(-v)); }
__device__ __forceinline__ float tanh_fast(float v) {
  return 2.0f / (1.0f + __expf(-2.0f * v)) - 1.0f;
}
}  // namespace

// A-operand layout (bf16, per m89-verified 16x16x32 fragment maps):
//   Abuf row = batch row (16), k = [x(0..23) | h(24..63)], swizzle idx^=(row&7)<<3.
// Gate wave w (0..2): computes zone tiles r,z,nx,nh for u = w*16+lm (masked u<40).
// Lane (lq,lm) owns D rows lq*4+0..3 of unit u for ALL 4 zones -> in-lane gate math,
// fp32 h state in registers, one barrier per step.
__global__ __launch_bounds__(NT) void gru_mfma4(
    const float* __restrict__ x, const float* __restrict__ Wih,
    const float* __restrict__ Whh, const float* __restrict__ bih,
    const float* __restrict__ bhh, const float* __restrict__ Wfc,
    const float* __restrict__ bfc, float* __restrict__ out,
    float* __restrict__ hid) {
  __shared__ __align__(16) unsigned short Abuf[2 * 1024];

  const int tid = threadIdx.x;
  const int l   = tid & 63;
  const int w   = tid >> 6;
  const int lm  = l & 15;
  const int lq  = l >> 4;
  const int gb0 = blockIdx.x * R;

  reinterpret_cast<uint4*>(Abuf)[tid] = make_uint4(0, 0, 0, 0);  // zero both buffers

  const int aBase0 = ((lm * 64 + lq * 8)      ^ ((lm & 7) << 3));
  const int aBase1 = ((lm * 64 + lq * 8 + 32) ^ ((lm & 7) << 3));

  // ---------------- gate role (waves 0..2) ----------------
  short8 B[4][2];
  float bias[4] = {0, 0, 0, 0};
  float hold[4] = {0, 0, 0, 0};
  int aw[4] = {0, 0, 0, 0};
  int u = 0;
  bool gvalid = false;
  if (w < 3) {
    u = w * 16 + lm;
    gvalid = (u < H);
#pragma unroll
    for (int z = 0; z < 4; ++z) {
#pragma unroll
      for (int kt = 0; kt < 2; ++kt) {
        short8 b;
#pragma unroll
        for (int j = 0; j < 8; ++j) {
          const int k = kt * 32 + lq * 8 + j;
          float v = 0.0f;
          if (gvalid) {
            if (z == 0)      v = (k < 24) ? Wih[u * 24 + k]          : Whh[u * 40 + (k - 24)];
            else if (z == 1) v = (k < 24) ? Wih[(40 + u) * 24 + k]   : Whh[(40 + u) * 40 + (k - 24)];
            else if (z == 2) v = (k < 24) ? Wih[(80 + u) * 24 + k]   : 0.0f;
            else             v = (k < 24) ? 0.0f                     : Whh[(80 + u) * 40 + (k - 24)];
          }
          b[j] = (short)f2bf(v);
        }
        B[z][kt] = b;
      }
    }
    if (gvalid) {
      bias[0] = bih[u] + bhh[u];
      bias[1] = bih[40 + u] + bhh[40 + u];
      bias[2] = bih[80 + u];           // n input bias
      bias[3] = bhh[80 + u];           // n hidden bias (scaled by r)
    }
#pragma unroll
    for (int i = 0; i < 4; ++i)
      aw[i] = (((lq * 4 + i) * 64 + 24 + u) ^ (((lq * 4 + i) & 7) << 3));
  }

  // ---------------- FC + x role (wave 3) ----------------
  short8 F[2][2];
  float biasF[2] = {0, 0};
  float* orow[4] = {nullptr, nullptr, nullptr, nullptr};
  const float* xp0 = nullptr;
  const float* xp1 = nullptr;
  int xw0 = 0, xw1 = 0;
  bool x1v = false;
  float4 xA0 = make_float4(0,0,0,0), xA1 = make_float4(0,0,0,0);
  float4 xB0 = make_float4(0,0,0,0), xB1 = make_float4(0,0,0,0);
  if (w == 3) {
#pragma unroll
    for (int f = 0; f < 2; ++f) {
      const int o = f * 16 + lm;
#pragma unroll
      for (int kt = 0; kt < 2; ++kt) {
        short8 b;
#pragma unroll
        for (int j = 0; j < 8; ++j) {
          const int k = kt * 32 + lq * 8 + j;
          const float v = (o < NOUT && k >= 24) ? Wfc[o * H + (k - 24)] : 0.0f;
          b[j] = (short)f2bf(v);
        }
        F[f][kt] = b;
      }
      biasF[f] = (o < NOUT) ? bfc[o] : 0.0f;
    }
#pragma unroll
    for (int i = 0; i < 4; ++i)
      orow[i] = out + ((size_t)(gb0 + lq * 4 + i) * SEQT) * NOUT;

    // x staging: 96 float4 chunks (16 rows x 6), items l and 64+l (l<32)
    const int i0 = l, i1 = 64 + l;
    const int xr0 = i0 / 6, xc0 = (i0 - xr0 * 6) * 4;
    const int xr1 = i1 / 6, xc1 = (i1 - xr1 * 6) * 4;
    x1v = (l < 32);
    xp0 = x + ((size_t)(gb0 + xr0) * SEQT) * INSZ + xc0;
    if (x1v) xp1 = x + ((size_t)(gb0 + xr1) * SEQT) * INSZ + xc1;
    xw0 = ((xr0 * 64 + xc0) ^ ((xr0 & 7) << 3));
    xw1 = ((xr1 * 64 + xc1) ^ ((xr1 & 7) << 3));
  }

  __syncthreads();  // Abuf zeroed

  if (w == 3) {  // stage x(0) into buf0; prefetch x(1), x(2) into regs
    const float4 v0 = ld4(xp0);
    *reinterpret_cast<uint2*>(&Abuf[xw0]) = make_uint2(
        (unsigned)f2bf(v0.x) | ((unsigned)f2bf(v0.y) << 16),
        (unsigned)f2bf(v0.z) | ((unsigned)f2bf(v0.w) << 16));
    if (x1v) {
      const float4 v1 = ld4(xp1);
      *reinterpret_cast<uint2*>(&Abuf[xw1]) = make_uint2(
          (unsigned)f2bf(v1.x) | ((unsigned)f2bf(v1.y) << 16),
          (unsigned)f2bf(v1.z) | ((unsigned)f2bf(v1.w) << 16));
    }
    xA0 = ld4(xp0 + 1 * INSZ);
    xB0 = ld4(xp0 + 2 * INSZ);
    if (x1v) { xA1 = ld4(xp1 + 1 * INSZ); xB1 = ld4(xp1 + 2 * INSZ); }
  }
  __syncthreads();  // x(0) staged

#define GATE_STEP(BO, NBO)                                                      \
  if (w < 3) {                                                                  \
    const short8 A0 = *reinterpret_cast<const short8*>(&Abuf[(BO) + aBase0]);   \
    const short8 A1 = *reinterpret_cast<const short8*>(&Abuf[(BO) + aBase1]);   \
    f32x4 ar = {bias[0], bias[0], bias[0], bias[0]};                            \
    f32x4 az = {bias[1], bias[1], bias[1], bias[1]};                            \
    f32x4 ax = {bias[2], bias[2], bias[2], bias[2]};                            \
    f32x4 ah = {bias[3], bias[3], bias[3], bias[3]};                            \
    ar = __builtin_amdgcn_mfma_f32_16x16x32_bf16(A0, B[0][0], ar, 0, 0, 0);     \
    az = __builtin_amdgcn_mfma_f32_16x16x32_bf16(A0, B[1][0], az, 0, 0, 0);     \
    ax = __builtin_amdgcn_mfma_f32_16x16x32_bf16(A0, B[2][0], ax, 0, 0, 0);     \
    ah = __builtin_amdgcn_mfma_f32_16x16x32_bf16(A0, B[3][0], ah, 0, 0, 0);     \
    ar = __builtin_amdgcn_mfma_f32_16x16x32_bf16(A1, B[0][1], ar, 0, 0, 0);     \
    az = __builtin_amdgcn_mfma_f32_16x16x32_bf16(A1, B[1][1], az, 0, 0, 0);     \
    ax = __builtin_amdgcn_mfma_f32_16x16x32_bf16(A1, B[2][1], ax, 0, 0, 0);     \
    ah = __builtin_amdgcn_mfma_f32_16x16x32_bf16(A1, B[3][1], ah, 0, 0, 0);     \
    _Pragma("unroll")                                                           \
    for (int i = 0; i < 4; ++i) {                                               \
      const float rr = sigm(ar[i]);                                             \
      const float zz = sigm(az[i]);                                             \
      const float nn = tanh_fast(ax[i] + rr * ah[i]);                           \
      const float h  = (1.0f - zz) * nn + zz * hold[i];                         \
      hold[i] = h;                                                              \
      if (gvalid) Abuf[(NBO) + aw[i]] = f2bf(h);                                \
    }                                                                           \
  }

#define XSTAGE(T, NBO, XS0, XS1)                                                \
  if (w == 3) {                                                                 \
    *reinterpret_cast<uint2*>(&Abuf[(NBO) + xw0]) = make_uint2(                 \
        (unsigned)f2bf(XS0.x) | ((unsigned)f2bf(XS0.y) << 16),                  \
        (unsigned)f2bf(XS0.z) | ((unsigned)f2bf(XS0.w) << 16));                 \
    if (x1v)                                                                    \
      *reinterpret_cast<uint2*>(&Abuf[(NBO) + xw1]) = make_uint2(               \
          (unsigned)f2bf(XS1.x) | ((unsigned)f2bf(XS1.y) << 16),                \
          (unsigned)f2bf(XS1.z) | ((unsigned)f2bf(XS1.w) << 16));               \
    if ((T) + 3 < SEQT) {                                                       \
      XS0 = ld4(xp0 + (size_t)((T) + 3) * INSZ);                                \
      if (x1v) XS1 = ld4(xp1 + (size_t)((T) + 3) * INSZ);                       \
    }                                                                           \
  }

#define FC_STEP(T, NBO)                                                         \
  if (w == 3) {                                                                 \
    const short8 hA0 = *reinterpret_cast<const short8*>(&Abuf[(NBO) + aBase0]); \
    const short8 hA1 = *reinterpret_cast<const short8*>(&Abuf[(NBO) + aBase1]); \
    f32x4 f0 = {biasF[0], biasF[0], biasF[0], biasF[0]};                        \
    f32x4 f1 = {biasF[1], biasF[1], biasF[1], biasF[1]};                        \
    f0 = __builtin_amdgcn_mfma_f32_16x16x32_bf16(hA0, F[0][0], f0, 0, 0, 0);    \
    f1 = __builtin_amdgcn_mfma_f32_16x16x32_bf16(hA0, F[1][0], f1, 0, 0, 0);    \
    f0 = __builtin_amdgcn_mfma_f32_16x16x32_bf16(hA1, F[0][1], f0, 0, 0, 0);    \
    f1 = __builtin_amdgcn_mfma_f32_16x16x32_bf16(hA1, F[1][1], f1, 0, 0, 0);    \
    _Pragma("unroll")                                                           \
    for (int i = 0; i < 4; ++i) {                                               \
      orow[i][(size_t)(T) * NOUT + lm] = sigm(f0[i]);                           \
      if (lm < 8) orow[i][(size_t)(T) * NOUT + 16 + lm] = sigm(f1[i]);          \
    }                                                                           \
  }

  for (int tt = 0; tt < SEQT; tt += 2) {
    // step t = tt (even): cur buf 0, next buf 1
    GATE_STEP(0, 1024)
    XSTAGE(tt, 1024, xA0, xA1)
    __syncthreads();
    FC_STEP(tt, 1024)
    // step t = tt+1 (odd): cur buf 1, next buf 0
    GATE_STEP(1024, 0)
    XSTAGE(tt + 1, 0, xB0, xB1)
    __syncthreads();
    FC_STEP(tt + 1, 0)
  }

  // final hidden state from registers
  if (w < 3 && gvalid) {
#pragma unroll
    for (int i = 0; i < 4; ++i)
      hid[(size_t)(gb0 + lq * 4 + i) * H + u] = hold[i];
  }
}

extern "C" void kernel_launch(void* const* d_in, const int* in_sizes, int n_in,
                              void* d_out, int out_size, void* d_ws, size_t ws_size,
                              hipStream_t stream) {
  const float* x   = (const float*)d_in[0];
  const float* Wih = (const float*)d_in[1];
  const float* Whh = (const float*)d_in[2];
  const float* bih = (const float*)d_in[3];
  const float* bhh = (const float*)d_in[4];
  const float* Wfc = (const float*)d_in[5];
  const float* bfc = (const float*)d_in[6];
  float* out = (float*)d_out;
  float* hid = out + (size_t)BATCH * SEQT * NOUT;

  dim3 grid(BATCH / R);
  dim3 block(NT);
  hipLaunchKernelGGL(gru_mfma4, grid, block, 0, stream,
                     x, Wih, Whh, bih, bhh, Wfc, bfc, out, hid);
}